// Round 8
// baseline (635.319 us; speedup 1.0000x reference)
//
#include <hip/hip_runtime.h>
#include <cfloat>

#define NROW   256      // B*E rows
#define RLEN   65536    // N*N elements per row
#define TPB    1024
#define KPT    16       // float4 groups per thread (16*4 = 64 elems)
#define REGS   8        // candidate slots per thread (values in VGPRs)
#define MAXC   (TPB*REGS)   // 8192
#define NITER  64       // scan length (local_k)
#define KSEL   64       // top-k
#define THETA_OFF 8.0f  // initial candidate threshold: M0 - 8.0

// Zero the 64 MB output (float4 stores, coalesced). Runs before the main kernel.
__global__ void __launch_bounds__(TPB)
gumbel_zero_kernel(float4* __restrict__ out) {
    size_t i = (size_t)blockIdx.x * TPB + threadIdx.x;
    out[i] = make_float4(0.f, 0.f, 0.f, 0.f);
}

// R8 = R7 with the spill removed. R7 kept rcur/rkh/ridx (24 regs) + stream
// temps against a 64-VGPR allocator cap (1024-thr blocks) -> ~49 dwords/thread
// scratch (51.7 MB WRITE/dispatch) reloaded inside the scan loop. Here only
// rcur[8] lives in VGPRs; khot lives in LDS (cand_kv, aliased staging->khot;
// slot sl owned by thread sl%1024 -> all kv RMW is same-thread) and idx stays
// in LDS until selection. Phase A additionally skips kh+=o under the SAME
// y>pt2 gate as the correction: skipped o <= e^-18.03 ~ 1.5e-8, khot error
// <= 64*1.5e-8 ~ 1e-6 (rank gap >= 1e-4) and the cur trajectory is
// BIT-IDENTICAL to R4/R6/R7 (all passed absmax 0.0).
__global__ void __launch_bounds__(TPB)
GumbelSampler_2482491097709_kernel(const float* __restrict__ scores,
                                   const float* __restrict__ gumbel,
                                   float* __restrict__ out)
{
    __shared__ float s_A[16];       // scan max partials
    __shared__ float s_B[16];       // scan sum partials
    __shared__ float s_EA[16];      // collect/expansion max partials
    __shared__ float s_EB[16];      // collect/expansion sum partials
    __shared__ float s_SV[2][16];   // selection val partials (round parity)
    __shared__ int   s_SI[2][16];   // selection idx partials
    __shared__ float s_mx[NITER];   // recorded 10*max(flat_t) (for backfill)
    __shared__ float s_rcp[NITER];  // recorded 1/S_t (for backfill)
    __shared__ int   s_cnt;
    __shared__ int   cand_idx[MAXC];
    __shared__ float cand_kv[MAXC]; // staging value, then accumulated khot

    const int tid  = threadIdx.x;
    const int lane = tid & 63;
    const int wid  = tid >> 6;

    // XCD swizzle: co-locate the 4 e-blocks of each b on one XCD (perf only).
    const int q    = blockIdx.x;
    const int xcd  = q & 7;
    const int slot = q >> 3;
    const int b    = xcd * 8 + (slot & 7);
    const int e    = slot >> 3;
    const int r    = b * 4 + e;

    const float*  __restrict__ srow = scores + (size_t)b * RLEN * 4 + e;
    const float4* __restrict__ g4   = (const float4*)(gumbel + (size_t)r * RLEN);

    // ---- Pass 1 (all 16 waves): block max M0 ----
    float lm = -FLT_MAX;
    for (int k = 0; k < KPT; ++k) {
        int p4 = tid + k * TPB;
        float4 g = g4[p4];
        int p = p4 * 4;
        float v0 = srow[(size_t)(p + 0) * 4] + g.x;
        float v1 = srow[(size_t)(p + 1) * 4] + g.y;
        float v2 = srow[(size_t)(p + 2) * 4] + g.z;
        float v3 = srow[(size_t)(p + 3) * 4] + g.w;
        lm = fmaxf(lm, fmaxf(fmaxf(v0, v1), fmaxf(v2, v3)));
    }
#pragma unroll
    for (int o = 32; o; o >>= 1) lm = fmaxf(lm, __shfl_xor(lm, o));
    if (lane == 0) s_A[wid] = lm;
    __syncthreads();
    float M0 = s_A[0];
#pragma unroll
    for (int w = 1; w < 16; ++w) M0 = fmaxf(M0, s_A[w]);   // uniform (exact max)
    const float C = M0 * 10.0f;          // anchor for the frozen-tail U only

    // ---- Pass 2 (all 16 waves): collect candidates >= theta; Mu/U of rest ----
    float theta = M0 - THETA_OFF;
    int cnt;
    while (true) {
        __syncthreads();                 // prior s_cnt / s_A reads done
        if (tid == 0) s_cnt = 0;
        __syncthreads();
        float mu = -FLT_MAX, u = 0.f;
        for (int k = 0; k < KPT; ++k) {
            int p4 = tid + k * TPB;
            float4 g = g4[p4];
            int p = p4 * 4;
            float vv[4] = { srow[(size_t)(p + 0) * 4] + g.x,
                            srow[(size_t)(p + 1) * 4] + g.y,
                            srow[(size_t)(p + 2) * 4] + g.z,
                            srow[(size_t)(p + 3) * 4] + g.w };
#pragma unroll
            for (int j = 0; j < 4; ++j) {
                float v = vv[j];
                if (v >= theta) {
                    int sl = atomicAdd(&s_cnt, 1);
                    if (sl < MAXC) { cand_idx[sl] = p + j; cand_kv[sl] = v; }
                } else {
                    mu = fmaxf(mu, v);
                    u += __expf(fmaf(v, 10.f, -C));
                }
            }
        }
#pragma unroll
        for (int o = 32; o; o >>= 1) {
            mu = fmaxf(mu, __shfl_xor(mu, o));
            u += __shfl_xor(u, o);
        }
        if (lane == 0) { s_EA[wid] = mu; s_EB[wid] = u; }
        __syncthreads();                 // staging + partials visible
        cnt = s_cnt;
        if (cnt <= MAXC) break;
        theta += 1.0f;                   // overflow retry (statistically never)
    }
    float Mu = -FLT_MAX, U = 0.f;
#pragma unroll
    for (int w = 0; w < 16; ++w) { Mu = fmaxf(Mu, s_EA[w]); U += s_EB[w]; }

    // ---- Owner pull: value -> rcur (VGPR); kv slot becomes khot acc = 0 ----
    float rcur[REGS];
#pragma unroll
    for (int j = 0; j < REGS; ++j) {
        int sl = tid + TPB * j;
        if (sl < cnt) {
            rcur[j] = cand_kv[sl];       // appender's write, barrier'd above
            cand_kv[sl] = 0.f;           // same-thread from here on
        } else rcur[j] = 0.f;
    }

    // ---- Scan: 64 iterations, R4-verbatim trajectory arithmetic ----
    bool  noexp = false;
    float pmx = 0.f, prcp = 0.f, pt2 = 0.f;
    for (int t = 0; t < NITER; ++t) {
        // Phase A: apply iteration t-1's onehot + correction, track max.
        // kh and correction both gated on y > pt2 (skip exact for cur;
        // kh skip error <= 1.5e-8/iter).
        float lmx = -FLT_MAX;
        if (t == 0) {
#pragma unroll
            for (int j = 0; j < REGS; ++j)
                if (tid + TPB * j < cnt) lmx = fmaxf(lmx, rcur[j]);
        } else {
#pragma unroll
            for (int j = 0; j < REGS; ++j) {
                int sl = tid + TPB * j;
                if (sl < cnt) {
                    float cur = rcur[j];
                    float y = fmaf(cur, 10.f, -pmx);
                    if (y > pt2) {
                        float o = __expf(y) * prcp;
                        cand_kv[sl] += o;               // same-thread LDS RMW
                        cur += __logf(fmaxf(1.f - o, FLT_MIN));
                        rcur[j] = cur;
                    }
                    lmx = fmaxf(lmx, cur);
                }
            }
        }
#pragma unroll
        for (int o = 32; o; o >>= 1) lmx = fmaxf(lmx, __shfl_xor(lmx, o));
        if (lane == 0) s_A[wid] = lmx;
        __syncthreads();
        float gm = s_A[0];
#pragma unroll
        for (int w = 1; w < 16; ++w) gm = fmaxf(gm, s_A[w]);   // uniform
        const float mx = fmaxf(gm, Mu) * 10.f;   // includes frozen-tail max

        // Phase B: sumexp at anchor mx (verbatim — full sum, fresh anchor)
        float ls = 0.f;
#pragma unroll
        for (int j = 0; j < REGS; ++j)
            if (tid + TPB * j < cnt) ls += __expf(fmaf(rcur[j], 10.f, -mx));
#pragma unroll
        for (int o = 32; o; o >>= 1) ls += __shfl_xor(ls, o);
        if (lane == 0) s_B[wid] = ls;
        __syncthreads();
        float S = 0.f;
#pragma unroll
        for (int w = 0; w < 16; ++w) S += s_B[w];              // uniform order
        if (U > 0.f) S += __expf(C - mx + __logf(U));  // frozen tail, log-space
        float lnse = __logf(S);
        float rcp  = 1.f / S;
        float t2   = lnse - 18.03f;
        if (tid == 0) { s_mx[t] = mx; s_rcp[t] = rcp; }  // history for backfill
        pmx = mx; prcp = rcp; pt2 = t2;

        // Expansion trigger (uniform): non-candidate onehot_t > 2^-25 requires
        // 10*Mu > Lse_t - 17.33; fire 2.67 early. Lands before iteration t+1
        // applies rcp_t corrections -> exact.
        if (!noexp && t < NITER - 1) {
            float Lse = mx + lnse;
            if (10.f * Mu > Lse - 20.f) {
                float thOld = theta;
                float thN   = (Lse - 26.f) * 0.1f;
                int   oldc  = cnt;
                float mu2 = -FLT_MAX, u2 = 0.f;
                for (int k = 0; k < KPT; ++k) {
                    int p4 = tid + k * TPB;
                    float4 g = g4[p4];
                    int p = p4 * 4;
                    float vv[4] = { srow[(size_t)(p + 0) * 4] + g.x,
                                    srow[(size_t)(p + 1) * 4] + g.y,
                                    srow[(size_t)(p + 2) * 4] + g.z,
                                    srow[(size_t)(p + 3) * 4] + g.w };
#pragma unroll
                    for (int j = 0; j < 4; ++j) {
                        float v = vv[j];
                        if (v < thOld) {
                            if (v >= thN) {
                                int sl = atomicAdd(&s_cnt, 1);
                                if (sl < MAXC) {
                                    cand_idx[sl] = p + j;
                                    cand_kv[sl]  = v;     // staged, bit-frozen
                                }
                            } else {
                                mu2 = fmaxf(mu2, v);
                                u2 += __expf(fmaf(v, 10.f, -C));
                            }
                        }
                    }
                }
#pragma unroll
                for (int o = 32; o; o >>= 1) {
                    mu2 = fmaxf(mu2, __shfl_xor(mu2, o));
                    u2 += __shfl_xor(u2, o);
                }
                if (lane == 0) { s_EA[wid] = mu2; s_EB[wid] = u2; }
                __syncthreads();         // appends + partials visible
                int newc = s_cnt;
                if (newc > MAXC) {
                    if (tid == 0) s_cnt = oldc;  // discard partial appends
                    noexp = true;                // uniform; never expand again
                } else {
                    float m2 = -FLT_MAX, uu = 0.f;
#pragma unroll
                    for (int w = 0; w < 16; ++w) {
                        m2 = fmaxf(m2, s_EA[w]); uu += s_EB[w];
                    }
                    Mu = m2; U = uu; theta = thN;
                    // owners pull new slots: value -> rcur, kv -> khot backfill
#pragma unroll
                    for (int j = 0; j < REGS; ++j) {
                        int sl = tid + TPB * j;
                        if (sl >= oldc && sl < newc) {
                            float v = cand_kv[sl];
                            rcur[j] = v;
                            float kb = 0.f;   // onehots tt<t (each < e^-20)
                            for (int tt = 0; tt < t; ++tt)
                                kb += __expf(fmaf(v, 10.f, -s_mx[tt])) * s_rcp[tt];
                            cand_kv[sl] = kb;
                        }
                    }
                    cnt = newc;
                }
            }
        }
    }
    // final iteration's onehot (t = NITER-1): accumulate only (gated, tiny-skip)
#pragma unroll
    for (int j = 0; j < REGS; ++j) {
        int sl = tid + TPB * j;
        if (sl < cnt) {
            float y = fmaf(rcur[j], 10.f, -pmx);
            if (y > pt2) cand_kv[sl] += __expf(y) * prcp;
        }
    }

    // ---- Pull khot + idx into regs for selection (scan regs now dead) ----
    float rkh[REGS]; int ridx[REGS];
#pragma unroll
    for (int j = 0; j < REGS; ++j) {
        int sl = tid + TPB * j;
        rkh[j]  = (sl < cnt) ? cand_kv[sl]  : -2.f;   // own writes; no barrier
        ridx[j] = (sl < cnt) ? cand_idx[sl] : 0x7fffffff;
    }

    // ---- Selection: 64 argmax rounds, jax top_k tie-break (val desc, idx asc).
    // 1 barrier/round via parity-buffered partials; claims in per-thread masks.
    unsigned cl = 0;
    float selv = -1.f; int seli = 0;
    for (int round = 0; round < KSEL; ++round) {
        const int par = round & 1;
        float bv = -1.f; int bi = 0x7fffffff;
#pragma unroll
        for (int j = 0; j < REGS; ++j) {
            if (!((cl >> j) & 1u)) {
                float v = rkh[j]; int i = ridx[j];
                if (v > bv || (v == bv && i < bi)) { bv = v; bi = i; }
            }
        }
#pragma unroll
        for (int o = 32; o; o >>= 1) {
            float ov = __shfl_xor(bv, o);
            int   oi = __shfl_xor(bi, o);
            if (ov > bv || (ov == bv && oi < bi)) { bv = ov; bi = oi; }
        }
        if (lane == 0) { s_SV[par][wid] = bv; s_SI[par][wid] = bi; }
        __syncthreads();
        float Bv = s_SV[par][0]; int Bi = s_SI[par][0];
#pragma unroll
        for (int w = 1; w < 16; ++w) {
            float v = s_SV[par][w]; int i = s_SI[par][w];
            if (v > Bv || (v == Bv && i < Bi)) { Bv = v; Bi = i; }
        }
        if (tid == round) { selv = Bv; seli = Bi; }
        if (Bv >= 0.f) {              // owner claims (idx unique => one claimer)
#pragma unroll
            for (int j = 0; j < REGS; ++j)
                if (!((cl >> j) & 1u) && rkh[j] == Bv && ridx[j] == Bi)
                    cl |= 1u << j;
        }
    }

    // ---- Scatter: thread k writes round-k winner; out pre-zeroed ----
    if (tid < KSEL && selv >= 0.f) {
        out[((size_t)b * RLEN + (size_t)seli) * 4 + e] = (1.f - selv) + selv;
    }
}

extern "C" void kernel_launch(void* const* d_in, const int* in_sizes, int n_in,
                              void* d_out, int out_size, void* d_ws, size_t ws_size,
                              hipStream_t stream) {
    const float* scores = (const float*)d_in[0];   // [B=64, N=256, N=256, E=4] f32
    const float* gumbel = (const float*)d_in[1];   // [B*E=256, N*N=65536] f32
    float* out = (float*)d_out;                    // [B, N, N, E] f32

    int nvec4 = out_size / 4;
    int zgrid = (nvec4 + TPB - 1) / TPB;
    gumbel_zero_kernel<<<zgrid, TPB, 0, stream>>>((float4*)out);
    GumbelSampler_2482491097709_kernel<<<NROW, TPB, 0, stream>>>(scores, gumbel, out);
}

// Round 9
// 478.430 us; speedup vs baseline: 1.3279x; 1.3279x over previous
//
#include <hip/hip_runtime.h>
#include <cfloat>

#define NROW   256      // B*E rows
#define RLEN   65536    // N*N elements per row
#define TPB    1024
#define KPT    16       // float4 groups per thread (16*4 = 64 elems)
#define REGS   8        // candidate slots per thread (values in VGPRs)
#define MAXC   (TPB*REGS)   // 8192
#define NITER  64       // scan length (local_k)
#define KSEL   64       // top-k
#define THETA_OFF 8.0f  // initial candidate threshold: M0 - 8.0
#define TCAP   256      // tie-list capacity

// R9 = R8 scan (absmax 0.0 x4) + two structural fixes:
// (1) LDS sized ~90 KB (> 160/2 KB) so only 1 block/CU fits -> grid spreads
//     over all 256 CUs. At R7/R8's 67 KB the dispatcher could pack 2 blocks/CU
//     on half the CUs (occupancy fell 47%->38%, wall time pinned ~530us
//     regardless of 8x scan-work differences between R4 and R8).
// (2) 64-round argmax selection (~10k VALU inst/thread) replaced by an exact
//     3-pass radix-histogram rank selection on __float_as_uint(khot) keys
//     (monotone for kh>=0): find the exact 64th-largest key K* and residual
//     rank; emit all key>K* plus the (need) smallest-index ties == jax top_k.
__global__ void __launch_bounds__(TPB)
GumbelSampler_2482491097709_kernel(const float* __restrict__ scores,
                                   const float* __restrict__ gumbel,
                                   float* __restrict__ out)
{
    __shared__ float s_A[16];       // scan max partials
    __shared__ float s_B[16];       // scan sum partials
    __shared__ float s_EA[16];      // collect/expansion max partials
    __shared__ float s_EB[16];      // collect/expansion sum partials
    __shared__ float s_mx[NITER];   // recorded 10*max(flat_t) (for backfill)
    __shared__ float s_rcp[NITER];  // recorded 1/S_t (for backfill)
    __shared__ int   s_cnt;
    __shared__ int   s_selB;        // histogram: found bin (per pass)
    __shared__ int   s_selR;        // histogram: residual rank (per pass)
    __shared__ int   s_tcnt;
    __shared__ int   s_tie[TCAP];
    __shared__ int   s_hist[4096];  // 16 KB: passes use <=2048 bins; oversized
                                    // on purpose to push LDS past 80 KB
    __shared__ int   cand_idx[MAXC];
    __shared__ float cand_kv[MAXC]; // staging value, then accumulated khot

    const int tid  = threadIdx.x;
    const int lane = tid & 63;
    const int wid  = tid >> 6;

    // XCD swizzle: co-locate the 4 e-blocks of each b on one XCD (perf only).
    const int q    = blockIdx.x;
    const int xcd  = q & 7;
    const int slot = q >> 3;
    const int b    = xcd * 8 + (slot & 7);
    const int e    = slot >> 3;
    const int r    = b * 4 + e;

    const float*  __restrict__ srow = scores + (size_t)b * RLEN * 4 + e;
    const float4* __restrict__ g4   = (const float4*)(gumbel + (size_t)r * RLEN);

    // ---- Pass 1 (all 16 waves): block max M0 ----
    float lm = -FLT_MAX;
    for (int k = 0; k < KPT; ++k) {
        int p4 = tid + k * TPB;
        float4 g = g4[p4];
        int p = p4 * 4;
        float v0 = srow[(size_t)(p + 0) * 4] + g.x;
        float v1 = srow[(size_t)(p + 1) * 4] + g.y;
        float v2 = srow[(size_t)(p + 2) * 4] + g.z;
        float v3 = srow[(size_t)(p + 3) * 4] + g.w;
        lm = fmaxf(lm, fmaxf(fmaxf(v0, v1), fmaxf(v2, v3)));
    }
#pragma unroll
    for (int o = 32; o; o >>= 1) lm = fmaxf(lm, __shfl_xor(lm, o));
    if (lane == 0) s_A[wid] = lm;
    __syncthreads();
    float M0 = s_A[0];
#pragma unroll
    for (int w = 1; w < 16; ++w) M0 = fmaxf(M0, s_A[w]);   // uniform (exact max)
    const float C = M0 * 10.0f;          // anchor for the frozen-tail U only

    // ---- Pass 2 (all 16 waves): collect candidates >= theta; Mu/U of rest ----
    float theta = M0 - THETA_OFF;
    int cnt;
    while (true) {
        __syncthreads();                 // prior s_cnt / s_A reads done
        if (tid == 0) s_cnt = 0;
        __syncthreads();
        float mu = -FLT_MAX, u = 0.f;
        for (int k = 0; k < KPT; ++k) {
            int p4 = tid + k * TPB;
            float4 g = g4[p4];
            int p = p4 * 4;
            float vv[4] = { srow[(size_t)(p + 0) * 4] + g.x,
                            srow[(size_t)(p + 1) * 4] + g.y,
                            srow[(size_t)(p + 2) * 4] + g.z,
                            srow[(size_t)(p + 3) * 4] + g.w };
#pragma unroll
            for (int j = 0; j < 4; ++j) {
                float v = vv[j];
                if (v >= theta) {
                    int sl = atomicAdd(&s_cnt, 1);
                    if (sl < MAXC) { cand_idx[sl] = p + j; cand_kv[sl] = v; }
                } else {
                    mu = fmaxf(mu, v);
                    u += __expf(fmaf(v, 10.f, -C));
                }
            }
        }
#pragma unroll
        for (int o = 32; o; o >>= 1) {
            mu = fmaxf(mu, __shfl_xor(mu, o));
            u += __shfl_xor(u, o);
        }
        if (lane == 0) { s_EA[wid] = mu; s_EB[wid] = u; }
        __syncthreads();                 // staging + partials visible
        cnt = s_cnt;
        if (cnt <= MAXC) break;
        theta += 1.0f;                   // overflow retry (statistically never)
    }
    float Mu = -FLT_MAX, U = 0.f;
#pragma unroll
    for (int w = 0; w < 16; ++w) { Mu = fmaxf(Mu, s_EA[w]); U += s_EB[w]; }

    // ---- Owner pull: value -> rcur (VGPR); kv slot becomes khot acc = 0 ----
    float rcur[REGS];
#pragma unroll
    for (int j = 0; j < REGS; ++j) {
        int sl = tid + TPB * j;
        if (sl < cnt) {
            rcur[j] = cand_kv[sl];       // appender's write, barrier'd above
            cand_kv[sl] = 0.f;           // same-thread from here on
        } else rcur[j] = 0.f;
    }

    // ---- Scan: 64 iterations, R4-verbatim trajectory arithmetic ----
    bool  noexp = false;
    float pmx = 0.f, prcp = 0.f, pt2 = 0.f;
    for (int t = 0; t < NITER; ++t) {
        // Phase A: apply iteration t-1's onehot + correction, track max.
        // kh and correction both gated on y > pt2 (skip exact for cur;
        // kh skip error <= 1.5e-8/iter vs >=1e-4 rank gap).
        float lmx = -FLT_MAX;
        if (t == 0) {
#pragma unroll
            for (int j = 0; j < REGS; ++j)
                if (tid + TPB * j < cnt) lmx = fmaxf(lmx, rcur[j]);
        } else {
#pragma unroll
            for (int j = 0; j < REGS; ++j) {
                int sl = tid + TPB * j;
                if (sl < cnt) {
                    float cur = rcur[j];
                    float y = fmaf(cur, 10.f, -pmx);
                    if (y > pt2) {
                        float o = __expf(y) * prcp;
                        cand_kv[sl] += o;               // same-thread LDS RMW
                        cur += __logf(fmaxf(1.f - o, FLT_MIN));
                        rcur[j] = cur;
                    }
                    lmx = fmaxf(lmx, cur);
                }
            }
        }
#pragma unroll
        for (int o = 32; o; o >>= 1) lmx = fmaxf(lmx, __shfl_xor(lmx, o));
        if (lane == 0) s_A[wid] = lmx;
        __syncthreads();
        float gm = s_A[0];
#pragma unroll
        for (int w = 1; w < 16; ++w) gm = fmaxf(gm, s_A[w]);   // uniform
        const float mx = fmaxf(gm, Mu) * 10.f;   // includes frozen-tail max

        // Phase B: sumexp at anchor mx (verbatim — full sum, fresh anchor)
        float ls = 0.f;
#pragma unroll
        for (int j = 0; j < REGS; ++j)
            if (tid + TPB * j < cnt) ls += __expf(fmaf(rcur[j], 10.f, -mx));
#pragma unroll
        for (int o = 32; o; o >>= 1) ls += __shfl_xor(ls, o);
        if (lane == 0) s_B[wid] = ls;
        __syncthreads();
        float S = 0.f;
#pragma unroll
        for (int w = 0; w < 16; ++w) S += s_B[w];              // uniform order
        if (U > 0.f) S += __expf(C - mx + __logf(U));  // frozen tail, log-space
        float lnse = __logf(S);
        float rcp  = 1.f / S;
        float t2   = lnse - 18.03f;
        if (tid == 0) { s_mx[t] = mx; s_rcp[t] = rcp; }  // history for backfill
        pmx = mx; prcp = rcp; pt2 = t2;

        // Expansion trigger (uniform): non-candidate onehot_t > 2^-25 requires
        // 10*Mu > Lse_t - 17.33; fire 2.67 early. Lands before iteration t+1
        // applies rcp_t corrections -> exact.
        if (!noexp && t < NITER - 1) {
            float Lse = mx + lnse;
            if (10.f * Mu > Lse - 20.f) {
                float thOld = theta;
                float thN   = (Lse - 26.f) * 0.1f;
                int   oldc  = cnt;
                float mu2 = -FLT_MAX, u2 = 0.f;
                for (int k = 0; k < KPT; ++k) {
                    int p4 = tid + k * TPB;
                    float4 g = g4[p4];
                    int p = p4 * 4;
                    float vv[4] = { srow[(size_t)(p + 0) * 4] + g.x,
                                    srow[(size_t)(p + 1) * 4] + g.y,
                                    srow[(size_t)(p + 2) * 4] + g.z,
                                    srow[(size_t)(p + 3) * 4] + g.w };
#pragma unroll
                    for (int j = 0; j < 4; ++j) {
                        float v = vv[j];
                        if (v < thOld) {
                            if (v >= thN) {
                                int sl = atomicAdd(&s_cnt, 1);
                                if (sl < MAXC) {
                                    cand_idx[sl] = p + j;
                                    cand_kv[sl]  = v;     // staged, bit-frozen
                                }
                            } else {
                                mu2 = fmaxf(mu2, v);
                                u2 += __expf(fmaf(v, 10.f, -C));
                            }
                        }
                    }
                }
#pragma unroll
                for (int o = 32; o; o >>= 1) {
                    mu2 = fmaxf(mu2, __shfl_xor(mu2, o));
                    u2 += __shfl_xor(u2, o);
                }
                if (lane == 0) { s_EA[wid] = mu2; s_EB[wid] = u2; }
                __syncthreads();         // appends + partials visible
                int newc = s_cnt;
                if (newc > MAXC) {
                    if (tid == 0) s_cnt = oldc;  // discard partial appends
                    noexp = true;                // uniform; never expand again
                } else {
                    float m2 = -FLT_MAX, uu = 0.f;
#pragma unroll
                    for (int w = 0; w < 16; ++w) {
                        m2 = fmaxf(m2, s_EA[w]); uu += s_EB[w];
                    }
                    Mu = m2; U = uu; theta = thN;
                    // owners pull new slots: value -> rcur, kv -> khot backfill
#pragma unroll
                    for (int j = 0; j < REGS; ++j) {
                        int sl = tid + TPB * j;
                        if (sl >= oldc && sl < newc) {
                            float v = cand_kv[sl];
                            rcur[j] = v;
                            float kb = 0.f;   // onehots tt<t (each < e^-20)
                            for (int tt = 0; tt < t; ++tt)
                                kb += __expf(fmaf(v, 10.f, -s_mx[tt])) * s_rcp[tt];
                            cand_kv[sl] = kb;
                        }
                    }
                    cnt = newc;
                }
            }
        }
    }
    // final iteration's onehot (t = NITER-1): accumulate only (gated, tiny-skip)
#pragma unroll
    for (int j = 0; j < REGS; ++j) {
        int sl = tid + TPB * j;
        if (sl < cnt) {
            float y = fmaf(rcur[j], 10.f, -pmx);
            if (y > pt2) cand_kv[sl] += __expf(y) * prcp;
        }
    }
    __syncthreads();       // all khot final & visible to all threads

    // ---- Radix-histogram top-64 (exact, jax top_k tie-break) ----
    // Keys = __float_as_uint(khot), khot >= 0 -> bit order == value order.
    // kh == 0 slots are excluded (>=64 positive khot guaranteed: the true
    // top-64 each have khot >= 1.5e-5, far above the accumulate gate).
    // Pass bins: [31:21] (2048), [20:10] (2048), [9:0] (1024). After each
    // pass, wave 0 finds the bin holding descending-rank Rrem and the
    // residual rank within it. After pass 3: K* = exact 64th-largest key,
    // Rrem = number of ties (== K*) to take, smallest index first.
    unsigned prefix = 0;
    int Rrem = KSEL;
    for (int pass = 0; pass < 3; ++pass) {
        const int nbins = (pass == 2) ? 1024 : 2048;
        for (int i = tid; i < nbins; i += TPB) s_hist[i] = 0;
        __syncthreads();
#pragma unroll
        for (int j = 0; j < REGS; ++j) {
            int sl = tid + TPB * j;
            if (sl < cnt) {
                unsigned key = __float_as_uint(cand_kv[sl]);
                if (key != 0u) {
                    bool m; int bin;
                    if (pass == 0)      { m = true;                     bin = key >> 21; }
                    else if (pass == 1) { m = (key >> 21) == prefix;    bin = (key >> 10) & 2047; }
                    else                { m = (key >> 10) == prefix;    bin = key & 1023; }
                    if (m) atomicAdd(&s_hist[bin], 1);
                }
            }
        }
        __syncthreads();
        if (wid == 0) {
            int Rl = Rrem, found = -1;
            const int nch = nbins >> 6;
            for (int c = 0; c < nch && found < 0; ++c) {
                int bin = nbins - 1 - (c * 64 + lane);   // descending bins
                int h = s_hist[bin];
                int cum = h;
#pragma unroll
                for (int s2 = 1; s2 < 64; s2 <<= 1) {
                    int v = __shfl_up(cum, s2);
                    if (lane >= s2) cum += v;
                }
                unsigned long long mb = __ballot(cum >= Rl);
                if (mb) {
                    int fl = __ffsll(mb) - 1;            // first (highest) bin
                    int cumex = __shfl(cum, fl) - __shfl(h, fl);
                    found = nbins - 1 - (c * 64 + fl);
                    Rl -= cumex;                          // rank inside bin
                } else {
                    Rl -= __shfl(cum, 63);                // whole chunk above
                }
            }
            if (lane == 0) { s_selB = found; s_selR = Rl; }
        }
        __syncthreads();
        prefix = (prefix << ((pass == 2) ? 10 : 11)) | (unsigned)s_selB;
        Rrem = s_selR;
    }
    const unsigned Kstar = prefix;       // exact 64th-largest key
    const int need = Rrem;               // ties to take (>= 1)

    // ---- Emit: all key > K*; collect ties == K* ----
    if (tid == 0) s_tcnt = 0;
    __syncthreads();
#pragma unroll
    for (int j = 0; j < REGS; ++j) {
        int sl = tid + TPB * j;
        if (sl < cnt) {
            float kh = cand_kv[sl];
            unsigned key = __float_as_uint(kh);
            if (key > Kstar) {
                int p = cand_idx[sl];
                out[((size_t)b * RLEN + (size_t)p) * 4 + e] = (1.f - kh) + kh;
            } else if (key == Kstar) {
                int tp = atomicAdd(&s_tcnt, 1);
                if (tp < TCAP) s_tie[tp] = cand_idx[sl];
            }
        }
    }
    __syncthreads();
    // wave 0 picks the `need` smallest tie indices (typically need==1, T==1)
    if (wid == 0) {
        int T = s_tcnt < TCAP ? s_tcnt : TCAP;
        float kv = __uint_as_float(Kstar);
        float ov = (1.f - kv) + kv;
        for (int rdone = 0; rdone < need; ++rdone) {
            int bi = 0x7fffffff, bp = -1;
            for (int i = lane; i < T; i += 64) {
                int v = s_tie[i];
                if (v < bi) { bi = v; bp = i; }
            }
#pragma unroll
            for (int s2 = 32; s2; s2 >>= 1) {
                int oi = __shfl_xor(bi, s2);
                int op = __shfl_xor(bp, s2);
                if (oi < bi) { bi = oi; bp = op; }
            }
            if (lane == 0 && bi != 0x7fffffff) {
                out[((size_t)b * RLEN + (size_t)bi) * 4 + e] = ov;
                s_tie[bp] = 0x7fffffff;      // remove; wave-local LDS is ordered
            }
        }
    }
}

extern "C" void kernel_launch(void* const* d_in, const int* in_sizes, int n_in,
                              void* d_out, int out_size, void* d_ws, size_t ws_size,
                              hipStream_t stream) {
    const float* scores = (const float*)d_in[0];   // [B=64, N=256, N=256, E=4] f32
    const float* gumbel = (const float*)d_in[1];   // [B*E=256, N*N=65536] f32
    float* out = (float*)d_out;                    // [B, N, N, E] f32

    // DMA zero-fill (graph-capturable async memset), then sparse scatter.
    hipMemsetAsync(d_out, 0, (size_t)out_size * sizeof(float), stream);
    GumbelSampler_2482491097709_kernel<<<NROW, TPB, 0, stream>>>(scores, gumbel, out);
}